// Round 9
// baseline (266.878 us; speedup 1.0000x reference)
//
#include <hip/hip_runtime.h>
#include <math.h>

#define NQ 16384
#define MR 16384
#define JTILES (MR / 16)      // 1024
#define MSPLIT 32
#define JT (JTILES / MSPLIT)  // 32 j-tiles per split
#define CSTEP 8               // tiles per address-rebase group (8*512B fits imm)

typedef __attribute__((ext_vector_type(8))) short bf16x8;
typedef __attribute__((ext_vector_type(4))) float floatx4;

// round-to-nearest-even fp32 -> bf16 (bit pattern). No NaN/inf in this data.
__device__ __forceinline__ unsigned short bf16_rne(float f) {
    union { float f; unsigned u; } v; v.f = f;
    return (unsigned short)((v.u + 0x7FFFu + ((v.u >> 16) & 1u)) >> 16);
}
__device__ __forceinline__ float bf16_to_f32(unsigned short h) {
    union { unsigned u; float f; } v; v.u = ((unsigned)h) << 16;
    return v.f;
}
// split fp32 v into 3 bf16 terms: v = h + m + l (to ~2^-25 relative)
__device__ __forceinline__ void split3(float v, unsigned short& h,
                                       unsigned short& m, unsigned short& l) {
    h = bf16_rne(v);
    float r1 = v - bf16_to_f32(h);   // exact (Sterbenz)
    m = bf16_rne(r1);
    float r2 = r1 - bf16_to_f32(m);  // exact
    l = bf16_rne(r2);
}
// pack 8 u16 -> one 16B store (dst 16B-aligned)
__device__ __forceinline__ void store8(unsigned short* p, const unsigned short* s) {
    uint4 a;
    a.x = (unsigned)s[0] | ((unsigned)s[1] << 16);
    a.y = (unsigned)s[2] | ((unsigned)s[3] << 16);
    a.z = (unsigned)s[4] | ((unsigned)s[5] << 16);
    a.w = (unsigned)s[6] | ((unsigned)s[7] << 16);
    *(uint4*)p = a;
}
// monotone fp32 -> u32 (strict total-order preserving; no NaNs in this data)
__device__ __forceinline__ unsigned fmap(float f) {
    union { float f; unsigned u; } v; v.f = f;
    return (v.u & 0x80000000u) ? ~v.u : (v.u | 0x80000000u);
}

// Prep (separate kernel — R6/R7 spill lesson: never share the fat split3
// live-set with the MFMA loop's register budget). Splits xb into 3 bf16
// planes in swizzled B-fragment order (element (col,k) of tile t at
// t*256 + (k>>3)*128 + col*8 + (k&7)), writes TRANSPOSED xb2t[n][t] =
// ||xb[t*16+n]||^2 (same tree order as R2..R8 passing), inits keys.
__global__ __launch_bounds__(256) void prep_b(const float* __restrict__ xb,
                                              unsigned short* __restrict__ BH,
                                              unsigned short* __restrict__ BM,
                                              unsigned short* __restrict__ BL,
                                              float* __restrict__ xb2t,
                                              unsigned long long* __restrict__ keys) {
    int j = blockIdx.x * 256 + threadIdx.x;
    keys[j] = 0xFFFFFFFFFFFFFFFFull;
    const float4* r4 = (const float4*)xb + (size_t)j * 4;
    float4 v0 = r4[0], v1 = r4[1], v2 = r4[2], v3 = r4[3];
    float vals[16] = {v0.x, v0.y, v0.z, v0.w, v1.x, v1.y, v1.z, v1.w,
                      v2.x, v2.y, v2.z, v2.w, v3.x, v3.y, v3.z, v3.w};
    float s0 = v0.x * v0.x + v0.y * v0.y + v0.z * v0.z + v0.w * v0.w;
    float s1 = v1.x * v1.x + v1.y * v1.y + v1.z * v1.z + v1.w * v1.w;
    float s2 = v2.x * v2.x + v2.y * v2.y + v2.z * v2.z + v2.w * v2.w;
    float s3 = v3.x * v3.x + v3.y * v3.y + v3.z * v3.z + v3.w * v3.w;
    xb2t[(size_t)(j & 15) * JTILES + (j >> 4)] = (s0 + s1) + (s2 + s3);
    unsigned short h[16], m[16], l[16];
#pragma unroll
    for (int k = 0; k < 16; ++k) split3(vals[k], h[k], m[k], l[k]);
    size_t tb = (size_t)(j >> 4) * 256 + (size_t)(j & 15) * 8;
    store8(BH + tb, h);       store8(BH + tb + 128, h + 8);
    store8(BM + tb, m);       store8(BM + tb + 128, m + 8);
    store8(BL + tb, l);       store8(BL + tb + 128, l + 8);
}

// Main: barrier-free K-loop. Per wave 4 query-tiles x one 32-tile j-split;
// B fragments read DIRECTLY from global (L2-resident: 49KB/split, read by
// 64 blocks; no LDS, no __syncthreads, compiler free to pipeline loads).
// Score tile = 3 K-packed MFMAs, acc init = xb2[col] (via transposed xb2t):
//   MFMA1: A=[xh|xm] B=[bh|bh]   MFMA2: A=[xh|xm] B=[bm|bm]
//   MFMA3: A=[xh|xl] B=[bl|bh]   (x planes carry the -2)
// Epilogue: lex (value, j) wave-reduce + one packed-key atomicMin per row —
// exact argmin-with-lowest-index, identical winner to R8 (absmax 0).
// launch_bounds(256,5): VGPR cap ~102 >= est live ~90; all-constant loop
// bounds (runtime msplit was R7's spill trigger).
__global__ __launch_bounds__(256, 5) void nn_mfma(const float* __restrict__ x,
                                                  const unsigned short* __restrict__ BH,
                                                  const unsigned short* __restrict__ BM,
                                                  const unsigned short* __restrict__ BL,
                                                  const float* __restrict__ xb2t,
                                                  unsigned long long* __restrict__ keys) {
    int tid = threadIdx.x;
    int lane = tid & 63;
    int wave = tid >> 6;
    int qt0 = blockIdx.x * 16 + wave * 4;          // 4 q-tiles per wave
    int split = blockIdx.y;
    int t0 = split * JT;

    int n = lane & 15;                              // row (A) / col (B)
    int quad = lane >> 4;
    int halfk = quad & 1;                           // dim half 0..7 / 8..15
    bool low32 = lane < 32;                         // K slot 0..15 vs 16..31
    int eoff2 = halfk * 128 + n * 8;                // shorts, swizzled layout

    // A fragments in-register from raw x (same construction as R4..R8)
    bf16x8 A1[4], A3[4];
#pragma unroll
    for (int q = 0; q < 4; ++q) {
        const float* xr = x + ((size_t)(qt0 + q) * 16 + n) * 16 + halfk * 8;
        float4 u0 = ((const float4*)xr)[0];
        float4 u1 = ((const float4*)xr)[1];
        float e[8] = {u0.x, u0.y, u0.z, u0.w, u1.x, u1.y, u1.z, u1.w};
#pragma unroll
        for (int k = 0; k < 8; ++k) {
            unsigned short h, m, l;
            split3(-2.0f * e[k], h, m, l);
            A1[q][k] = (short)(low32 ? h : m);
            A3[q][k] = (short)(low32 ? h : l);
        }
    }

    // Per-lane B-fragment streams (global; coalesced 512B segments/plane)
    const unsigned short* b1p = BH + (size_t)t0 * 256 + eoff2;
    const unsigned short* b2p = BM + (size_t)t0 * 256 + eoff2;
    const unsigned short* b3p = (low32 ? BL : BH) + (size_t)t0 * 256 + eoff2;
    const float* xvp = xb2t + (size_t)n * JTILES + t0;  // contiguous in t

    float best[4][4];
    int bjt[4][4];
#pragma unroll
    for (int q = 0; q < 4; ++q)
#pragma unroll
        for (int r = 0; r < 4; ++r) { best[q][r] = INFINITY; bjt[q][r] = t0; }

    for (int c = 0; c < JT; c += CSTEP) {
        float xv8[8];
        *(float4*)&xv8[0] = *(const float4*)(xvp + c);
        *(float4*)&xv8[4] = *(const float4*)(xvp + c + 4);
#pragma unroll
        for (int u = 0; u < CSTEP; ++u) {
            int tt = c + u;
            int tg = t0 + tt;                       // global j-tile
            bf16x8 f1 = *(const bf16x8*)(b1p + tt * 256);
            bf16x8 f2 = *(const bf16x8*)(b2p + tt * 256);
            bf16x8 f3 = *(const bf16x8*)(b3p + tt * 256);
            float xv = xv8[u];
#pragma unroll
            for (int q = 0; q < 4; ++q) {
                floatx4 acc = {xv, xv, xv, xv};
                acc = __builtin_amdgcn_mfma_f32_16x16x32_bf16(A1[q], f1, acc, 0, 0, 0);
                acc = __builtin_amdgcn_mfma_f32_16x16x32_bf16(A1[q], f2, acc, 0, 0, 0);
                acc = __builtin_amdgcn_mfma_f32_16x16x32_bf16(A3[q], f3, acc, 0, 0, 0);
#pragma unroll
                for (int r = 0; r < 4; ++r) {
                    float s = acc[r];
                    if (s < best[q][r]) { best[q][r] = s; bjt[q][r] = tg; }
                }
            }
        }
    }

    // Cross-lane argmin per row (row = quad*4 + r); lex (value, j);
    // one device-scope atomicMin per row with the packed order-key.
#pragma unroll
    for (int q = 0; q < 4; ++q) {
#pragma unroll
        for (int r = 0; r < 4; ++r) {
            float v = best[q][r];
            int j = bjt[q][r] * 16 + n;
#pragma unroll
            for (int d = 1; d < 16; d <<= 1) {
                float ov = __shfl_xor(v, d, 64);
                int oj = __shfl_xor(j, d, 64);
                if (ov < v || (ov == v && oj < j)) { v = ov; j = oj; }
            }
            if (n == 0) {
                int gq = (qt0 + q) * 16 + quad * 4 + r;
                unsigned long long key =
                    ((unsigned long long)fmap(v) << 32) | (unsigned)j;
                atomicMin(&keys[gq], key);
            }
        }
    }
}

// Decode keys -> y gather.
__global__ __launch_bounds__(256) void nn_decode(const unsigned long long* __restrict__ keys,
                                                 const float* __restrict__ y,
                                                 float* __restrict__ out) {
    int q = blockIdx.x * 256 + threadIdx.x;
    if (q >= NQ) return;
    out[q] = y[(unsigned)(keys[q] & 0xFFFFFFFFu)];
}

extern "C" void kernel_launch(void* const* d_in, const int* in_sizes, int n_in,
                              void* d_out, int out_size, void* d_ws, size_t ws_size,
                              hipStream_t stream) {
    const float* x  = (const float*)d_in[0];   // [NQ, 16]
    const float* xb = (const float*)d_in[1];   // [MR, 16]
    const float* y  = (const float*)d_in[2];   // [MR]
    float* out = (float*)d_out;                // [NQ]

    // ws: planes 3*512KB + xb2t 64KB + keys 128KB = 1.73MB (R8 precedent)
    unsigned short* BH = (unsigned short*)d_ws;
    unsigned short* BM = BH + (size_t)MR * 16;
    unsigned short* BL = BM + (size_t)MR * 16;
    float* xb2t = (float*)(BL + (size_t)MR * 16);
    unsigned long long* keys = (unsigned long long*)(xb2t + MR);

    prep_b<<<MR / 256, 256, 0, stream>>>(xb, BH, BM, BL, xb2t, keys);
    dim3 grid(NQ / 256, MSPLIT);               // 64 x 32 = 2048 blocks
    nn_mfma<<<grid, 256, 0, stream>>>(x, BH, BM, BL, xb2t, keys);
    nn_decode<<<NQ / 256, 256, 0, stream>>>(keys, y, out);
}